// Round 6
// baseline (101.852 us; speedup 1.0000x reference)
//
#include <hip/hip_runtime.h>
#include <hip/hip_bf16.h>
#include <cstdint>
#include <cstddef>

typedef __attribute__((ext_vector_type(8))) short bf16x8;
typedef __attribute__((ext_vector_type(4))) float f32x4;

__device__ __forceinline__ unsigned short f2bf(float f) {
  union { float f; unsigned u; } v; v.f = f;
  unsigned r = v.u + 0x7FFFu + ((v.u >> 16) & 1u);
  return (unsigned short)(r >> 16);
}

__device__ __forceinline__ float bf2f(unsigned short h) {
  union { float f; unsigned u; } c; c.u = ((unsigned)h) << 16;
  return c.f;
}

__device__ __forceinline__ void gload_lds16(const void* g, void* l) {
  __builtin_amdgcn_global_load_lds(
      (const __attribute__((address_space(1))) unsigned int*)g,
      (__attribute__((address_space(3))) unsigned int*)l, 16, 0, 0);
}

__device__ __forceinline__ void st_agent(float* p, float v) {
  __hip_atomic_store(p, v, __ATOMIC_RELAXED, __HIP_MEMORY_SCOPE_AGENT);
}
__device__ __forceinline__ float ld_agent(const float* p) {
  return __hip_atomic_load(p, __ATOMIC_RELAXED, __HIP_MEMORY_SCOPE_AGENT);
}

// ---------------------------------------------------------------------------
// Single fused persistent kernel. 256 blocks x 512 thr, 147KB LDS -> exactly
// 1 block/CU (co-residency forced by LDS), grid == #CUs -> spin barrier safe.
//
// Phase A (per block): transpose one 64x64 W-tile -> Wt bf16 (pad 0);
//   norm+convert 32 x-rows -> xbf, rnorm; s += xn (device atomics).
// Global barrier: vmcnt(0) + per-block RELEASE atomicAdd (wbl2, writeback
//   only) + relaxed spin + single ACQUIRE (inv) -- one synchronized flush,
//   replacing two kernel-boundary flushes. (R4 showed scattered acq-inv
//   fences are catastrophic; synchronized ones are the grid.sync pattern.)
// Phase B: R5's T-stack GEMM (128cls x 256rows, BK=64, tri-buffer LDS,
//   depth-2 prefetch, counted vmcnt(6), XOR-swizzle) + softmax partials.
// Fixup: fence-free agent-store split-K merge (R5-proven); the 8th-arriving
//   block per row-block also computes dot(x_row, s) from its L2-hot B-panel.
// ---------------------------------------------------------------------------
#define LDSBUF 49152
#define NBLK 256

__global__ __launch_bounds__(512) void k_all(const float* __restrict__ x,
                                             const float* __restrict__ W,
                                             const float* __restrict__ bias,
                                             unsigned short* __restrict__ Wt,
                                             unsigned short* __restrict__ xbf,
                                             float* __restrict__ rnorm,
                                             float* __restrict__ s,
                                             int* __restrict__ cnt2,
                                             int* __restrict__ cnt,
                                             float* __restrict__ pm,
                                             float* __restrict__ pz,
                                             float* __restrict__ ps,
                                             float* __restrict__ out) {
  __shared__ __align__(16) char lds[147456];
  __shared__ int lastflag;

  int tid = threadIdx.x;
  int lane = tid & 63;
  int wid = tid >> 6;  // 0..7
  int b = blockIdx.x;

  // ===== Phase A1: W transpose, one 64x64 tile per block =====
  {
    float (*tile)[65] = (float(*)[65])lds;
    int k0 = (b & 15) * 64;
    int c0 = (b >> 4) * 64;
    int tx = tid & 63;
    int ty = tid >> 6;  // 0..7
#pragma unroll
    for (int i = 0; i < 8; ++i) {
      int r = i * 8 + ty;
      int c = c0 + tx;
      tile[r][tx] = (c < 1000) ? W[(size_t)(k0 + r) * 1000 + c] : 0.f;
    }
    __syncthreads();
#pragma unroll
    for (int i = 0; i < 8; ++i) {
      int ct = i * 8 + ty;
      Wt[(size_t)(c0 + ct) * 1024 + (k0 + tx)] = f2bf(tile[tx][ct]);
    }
  }

  // ===== Phase A2: norm/convert rows [32b, 32b+32), s partial =====
  {
    float (*sblk)[1024] = (float(*)[1024])(lds + 17408);  // 8x1024 f32
    float4 sacc[4];
#pragma unroll
    for (int j = 0; j < 4; ++j) sacc[j] = make_float4(0.f, 0.f, 0.f, 0.f);
#pragma unroll
    for (int r = 0; r < 4; ++r) {
      int row = b * 32 + wid * 4 + r;
      const float4* xr = (const float4*)(x + (size_t)row * 1024);
      float4 v[4];
      float ss = 0.f;
#pragma unroll
      for (int j = 0; j < 4; ++j) {
        v[j] = xr[lane + j * 64];
        ss += v[j].x * v[j].x + v[j].y * v[j].y + v[j].z * v[j].z + v[j].w * v[j].w;
      }
#pragma unroll
      for (int m = 1; m < 64; m <<= 1) ss += __shfl_xor(ss, m);
      float rn = 1.f / fmaxf(sqrtf(ss), 1e-8f);
      if (lane == 0) rnorm[row] = rn;
#pragma unroll
      for (int j = 0; j < 4; ++j) {
        ushort4 hv;
        hv.x = f2bf(v[j].x); hv.y = f2bf(v[j].y);
        hv.z = f2bf(v[j].z); hv.w = f2bf(v[j].w);
        ((ushort4*)(xbf + (size_t)row * 1024))[lane + j * 64] = hv;
        sacc[j].x += v[j].x * rn; sacc[j].y += v[j].y * rn;
        sacc[j].z += v[j].z * rn; sacc[j].w += v[j].w * rn;
      }
    }
#pragma unroll
    for (int j = 0; j < 4; ++j) ((float4*)sblk[wid])[j * 64 + lane] = sacc[j];
    __syncthreads();
#pragma unroll
    for (int d = tid; d < 1024; d += 512) {
      float t = 0.f;
#pragma unroll
      for (int w = 0; w < 8; ++w) t += sblk[w][d];
      atomicAdd(&s[d], t);  // device-scope RMW at coherence point
    }
  }

  // ===== Global barrier (release -> count -> spin -> acquire) =====
  asm volatile("s_waitcnt vmcnt(0)" ::: "memory");
  __syncthreads();
  if (tid == 0) {
    __hip_atomic_fetch_add(cnt2, 1, __ATOMIC_RELEASE, __HIP_MEMORY_SCOPE_AGENT);
    while (__hip_atomic_load(cnt2, __ATOMIC_RELAXED, __HIP_MEMORY_SCOPE_AGENT) < NBLK)
      __builtin_amdgcn_s_sleep(2);
    (void)__hip_atomic_load(cnt2, __ATOMIC_ACQUIRE, __HIP_MEMORY_SCOPE_AGENT);
  }
  __syncthreads();

  // ===== Phase B: GEMM (cls x rows) + softmax partials =====
  int wc = wid & 1;
  int wr = wid >> 1;
  int cb = b & 7;   // cls chunk -> XCD round-robin (A-panel L2 reuse)
  int rb = b >> 3;  // 0..31
  int C0 = cb * 128;
  int R0 = rb * 256;

  float bv[4][4];
#pragma unroll
  for (int mf = 0; mf < 4; ++mf)
#pragma unroll
    for (int q = 0; q < 4; ++q) {
      int cls_g = C0 + wc * 64 + mf * 16 + (lane >> 4) * 4 + q;
      bv[mf][q] = (cls_g < 1000) ? bias[cls_g] : -1e30f;
    }
  f32x4 acc[4][4];
#pragma unroll
  for (int mf = 0; mf < 4; ++mf)
#pragma unroll
    for (int nf = 0; nf < 4; ++nf)
#pragma unroll
      for (int q = 0; q < 4; ++q) acc[mf][nf][q] = bv[mf][q];

  const char* gA = (const char*)(Wt + (size_t)C0 * 1024);
  const char* gB = (const char*)(xbf + (size_t)R0 * 1024);
  int grow = lane >> 3;
  int gswz = ((lane & 7) ^ grow) << 4;

#define STA(kt, bb, r)                                                         \
  gload_lds16(gA + (size_t)((r) * 64 + wid * 8 + grow) * 2048 + (kt) * 128 +   \
                  gswz,                                                        \
              lds + (bb) * LDSBUF + (r) * 8192 + wid * 1024)
#define STB(kt, bb, r)                                                         \
  gload_lds16(gB + (size_t)((r) * 64 + wid * 8 + grow) * 2048 + (kt) * 128 +   \
                  gswz,                                                        \
              lds + (bb) * LDSBUF + 16384 + (r) * 8192 + wid * 1024)

  STA(0, 0, 0); STA(0, 0, 1); STB(0, 0, 0); STB(0, 0, 1); STB(0, 0, 2); STB(0, 0, 3);
  STA(1, 1, 0); STA(1, 1, 1); STB(1, 1, 0); STB(1, 1, 1); STB(1, 1, 2); STB(1, 1, 3);

  int rsw = (lane & 7) << 4;
  int kcol = (lane >> 4) * 16;

  auto ktile = [&](const char* A, const char* B, int nt, int nb, bool pf) {
    if (pf) { STA(nt, nb, 0); STA(nt, nb, 1); }
    bf16x8 a[4][2];
#pragma unroll
    for (int mf = 0; mf < 4; ++mf)
#pragma unroll
      for (int ks = 0; ks < 2; ++ks)
        a[mf][ks] = *(const bf16x8*)(A + (wc * 64 + mf * 16 + (lane & 15)) * 128 +
                                     ((ks * 64 + kcol) ^ rsw));
    {
      bf16x8 b0[2];
#pragma unroll
      for (int ks = 0; ks < 2; ++ks)
        b0[ks] = *(const bf16x8*)(B + (wr * 64 + 0 * 16 + (lane & 15)) * 128 +
                                  ((ks * 64 + kcol) ^ rsw));
      __builtin_amdgcn_s_setprio(1);
#pragma unroll
      for (int ks = 0; ks < 2; ++ks)
#pragma unroll
        for (int mf = 0; mf < 4; ++mf)
          acc[mf][0] = __builtin_amdgcn_mfma_f32_16x16x32_bf16(a[mf][ks], b0[ks],
                                                               acc[mf][0], 0, 0, 0);
      __builtin_amdgcn_s_setprio(0);
    }
    if (pf) { STB(nt, nb, 0); STB(nt, nb, 1); }
    {
      bf16x8 b1[2];
#pragma unroll
      for (int ks = 0; ks < 2; ++ks)
        b1[ks] = *(const bf16x8*)(B + (wr * 64 + 1 * 16 + (lane & 15)) * 128 +
                                  ((ks * 64 + kcol) ^ rsw));
      __builtin_amdgcn_s_setprio(1);
#pragma unroll
      for (int ks = 0; ks < 2; ++ks)
#pragma unroll
        for (int mf = 0; mf < 4; ++mf)
          acc[mf][1] = __builtin_amdgcn_mfma_f32_16x16x32_bf16(a[mf][ks], b1[ks],
                                                               acc[mf][1], 0, 0, 0);
      __builtin_amdgcn_s_setprio(0);
    }
    if (pf) { STB(nt, nb, 2); STB(nt, nb, 3); }
    {
      bf16x8 b2[2];
#pragma unroll
      for (int ks = 0; ks < 2; ++ks)
        b2[ks] = *(const bf16x8*)(B + (wr * 64 + 2 * 16 + (lane & 15)) * 128 +
                                  ((ks * 64 + kcol) ^ rsw));
      __builtin_amdgcn_s_setprio(1);
#pragma unroll
      for (int ks = 0; ks < 2; ++ks)
#pragma unroll
        for (int mf = 0; mf < 4; ++mf)
          acc[mf][2] = __builtin_amdgcn_mfma_f32_16x16x32_bf16(a[mf][ks], b2[ks],
                                                               acc[mf][2], 0, 0, 0);
      __builtin_amdgcn_s_setprio(0);
    }
    {
      bf16x8 b3[2];
#pragma unroll
      for (int ks = 0; ks < 2; ++ks)
        b3[ks] = *(const bf16x8*)(B + (wr * 64 + 3 * 16 + (lane & 15)) * 128 +
                                  ((ks * 64 + kcol) ^ rsw));
      __builtin_amdgcn_s_setprio(1);
#pragma unroll
      for (int ks = 0; ks < 2; ++ks)
#pragma unroll
        for (int mf = 0; mf < 4; ++mf)
          acc[mf][3] = __builtin_amdgcn_mfma_f32_16x16x32_bf16(a[mf][ks], b3[ks],
                                                               acc[mf][3], 0, 0, 0);
      __builtin_amdgcn_s_setprio(0);
    }
  };

  for (int t = 0; t < 15; ++t) {
    asm volatile("s_waitcnt vmcnt(6)" ::: "memory");
    __builtin_amdgcn_s_barrier();
    asm volatile("" ::: "memory");
    const char* A = lds + (t % 3) * LDSBUF;
    ktile(A, A + 16384, t + 2, (t + 2) % 3, t < 14);
  }
  asm volatile("s_waitcnt vmcnt(0)" ::: "memory");
  __builtin_amdgcn_s_barrier();
  asm volatile("" ::: "memory");
  {
    const char* A = lds + (15 % 3) * LDSBUF;
    ktile(A, A + 16384, 0, 0, false);
  }

  // softmax partial stats (per wave 64 cls), merge wc halves via LDS
  __syncthreads();
  float* mm = (float*)lds;
  float* zz = mm + 512;
  float* sv = zz + 512;
#pragma unroll
  for (int nf = 0; nf < 4; ++nf) {
    float m1 = -1e30f;
#pragma unroll
    for (int mf = 0; mf < 4; ++mf)
#pragma unroll
      for (int q = 0; q < 4; ++q) m1 = fmaxf(m1, acc[mf][nf][q]);
    m1 = fmaxf(m1, __shfl_xor(m1, 16));
    m1 = fmaxf(m1, __shfl_xor(m1, 32));
    float z1 = 0.f, s1 = 0.f;
#pragma unroll
    for (int mf = 0; mf < 4; ++mf)
#pragma unroll
      for (int q = 0; q < 4; ++q) {
        float tt = acc[mf][nf][q] - m1;
        float e = expf(tt);
        z1 += e;
        s1 += e * tt;
      }
    z1 += __shfl_xor(z1, 16); z1 += __shfl_xor(z1, 32);
    s1 += __shfl_xor(s1, 16); s1 += __shfl_xor(s1, 32);
    if (lane < 16) {
      int r = wr * 64 + nf * 16 + lane;
      mm[wc * 256 + r] = m1;
      zz[wc * 256 + r] = z1;
      sv[wc * 256 + r] = s1;
    }
  }
  __syncthreads();
  if (tid < 256) {
    float m0 = mm[tid], mA = mm[256 + tid];
    float z0 = zz[tid], zA = zz[256 + tid];
    float s0 = sv[tid], sA = sv[256 + tid];
    float M = fmaxf(m0, mA);
    float e0 = expf(m0 - M), e1 = expf(mA - M);
    float Z = z0 * e0 + zA * e1;
    float S = e0 * (s0 + (m0 - M) * z0) + e1 * (sA + (mA - M) * zA);
    size_t o = (size_t)cb * 8192 + R0 + tid;
    st_agent(&pm[o], M);
    st_agent(&pz[o], Z);
    st_agent(&ps[o], S);
  }

  // ===== Fence-free split-K fixup (8th-arriving block per rb) =====
  asm volatile("s_waitcnt vmcnt(0)" ::: "memory");
  __syncthreads();
  if (tid == 0) lastflag = (atomicAdd(&cnt[rb], 1) == 7) ? 1 : 0;
  __syncthreads();
  if (lastflag) {
    // dot(x_row, s) for 256 rows: 2 threads/row, B-panel is L2-hot.
    float* dotl = (float*)(lds + 8192);
    int rr = tid >> 1, half = tid & 1;
    int row = R0 + rr;
    const bf16x8* xr = (const bf16x8*)(xbf + (size_t)row * 1024 + half * 512);
    const float4* sp = (const float4*)(s + half * 512);
    float d = 0.f;
#pragma unroll 8
    for (int j = 0; j < 64; ++j) {
      bf16x8 v = xr[j];
      float4 sa = sp[j * 2], sb = sp[j * 2 + 1];
      d += bf2f((unsigned short)v[0]) * sa.x + bf2f((unsigned short)v[1]) * sa.y +
           bf2f((unsigned short)v[2]) * sa.z + bf2f((unsigned short)v[3]) * sa.w +
           bf2f((unsigned short)v[4]) * sb.x + bf2f((unsigned short)v[5]) * sb.y +
           bf2f((unsigned short)v[6]) * sb.z + bf2f((unsigned short)v[7]) * sb.w;
    }
    d += __shfl_xor(d, 1);
    if (half == 0) dotl[rr] = d;
    __syncthreads();
    if (tid < 256) {
      int orow = R0 + tid;
      float mv[8], zv[8], svv[8];
      float M = -1e30f;
#pragma unroll
      for (int c = 0; c < 8; ++c) {
        mv[c] = ld_agent(&pm[(size_t)c * 8192 + orow]);
        zv[c] = ld_agent(&pz[(size_t)c * 8192 + orow]);
        svv[c] = ld_agent(&ps[(size_t)c * 8192 + orow]);
        M = fmaxf(M, mv[c]);
      }
      float Z = 0.f, S = 0.f;
#pragma unroll
      for (int c = 0; c < 8; ++c) {
        float e = expf(mv[c] - M);
        Z += zv[c] * e;
        S += e * (svv[c] + (mv[c] - M) * zv[c]);
      }
      float loss = S / Z - logf(Z);
      out[orow] = loss * dotl[tid] * rnorm[orow] * (1.f / 8192.f);
    }
  }
}

// ---------------------------------------------------------------------------
extern "C" void kernel_launch(void* const* d_in, const int* in_sizes, int n_in,
                              void* d_out, int out_size, void* d_ws, size_t ws_size,
                              hipStream_t stream) {
  (void)in_sizes; (void)n_in; (void)out_size; (void)ws_size;
  const float* x = (const float*)d_in[0];
  const float* W = (const float*)d_in[1];
  const float* b = (const float*)d_in[2];
  float* out = (float*)d_out;
  char* ws = (char*)d_ws;

  unsigned short* Wt = (unsigned short*)(ws + 0);           // 2 MiB
  unsigned short* xbf = (unsigned short*)(ws + 2097152);    // 16 MiB
  float* rnorm = (float*)(ws + 18874368);                   // 32 KiB
  float* s = (float*)(ws + 18907136);                       // 4 KiB
  int* cnt2 = (int*)(ws + 18911232);                        // 4 B (s+4096)
  int* cnt = (int*)(ws + 18911236);                         // 128 B
  float* pm = (float*)(ws + 18915328);                      // 256 KiB
  float* pz = (float*)(ws + 18915328 + 262144);
  float* ps = (float*)(ws + 18915328 + 524288);

  hipMemsetAsync(s, 0, 8192, stream);  // zeros s + cnt2 + cnt each replay
  k_all<<<NBLK, 512, 0, stream>>>(x, W, b, Wt, xbf, rnorm, s, cnt2, cnt,
                                  pm, pz, ps, out);
}

// Round 7
// 78.572 us; speedup vs baseline: 1.2963x; 1.2963x over previous
//
#include <hip/hip_runtime.h>
#include <hip/hip_bf16.h>
#include <cstdint>
#include <cstddef>

typedef __attribute__((ext_vector_type(8))) short bf16x8;
typedef __attribute__((ext_vector_type(4))) float f32x4;

__device__ __forceinline__ unsigned short f2bf(float f) {
  union { float f; unsigned u; } v; v.f = f;
  unsigned r = v.u + 0x7FFFu + ((v.u >> 16) & 1u);
  return (unsigned short)(r >> 16);
}

__device__ __forceinline__ float bf2f(unsigned short h) {
  union { float f; unsigned u; } c; c.u = ((unsigned)h) << 16;
  return c.f;
}

__device__ __forceinline__ void gload_lds16(const void* g, void* l) {
  __builtin_amdgcn_global_load_lds(
      (const __attribute__((address_space(1))) unsigned int*)g,
      (__attribute__((address_space(3))) unsigned int*)l, 16, 0, 0);
}

// Relaxed agent-scope ops: write-through/read at coherence point, NO
// buffer_wbl2 / buffer_inv (R4/R6 showed those are catastrophic in-kernel).
__device__ __forceinline__ void st_agent(float* p, float v) {
  __hip_atomic_store(p, v, __ATOMIC_RELAXED, __HIP_MEMORY_SCOPE_AGENT);
}
__device__ __forceinline__ void st_agent64(unsigned long long* p, unsigned long long v) {
  __hip_atomic_store(p, v, __ATOMIC_RELAXED, __HIP_MEMORY_SCOPE_AGENT);
}
__device__ __forceinline__ float ld_agent(const float* p) {
  return __hip_atomic_load(p, __ATOMIC_RELAXED, __HIP_MEMORY_SCOPE_AGENT);
}
__device__ __forceinline__ int ld_agent_i(const int* p) {
  return __hip_atomic_load(p, __ATOMIC_RELAXED, __HIP_MEMORY_SCOPE_AGENT);
}

// ---------------------------------------------------------------------------
// Single fused kernel, NO global barrier. 256 blocks x 512 thr, 147KB LDS
// (1 block/CU -> all blocks resident; spins are deadlock-free anyway since
// every block sets its flags unconditionally before any spin).
//
// Block (cb=b&7, rb=b>>3):
//  A-W: transpose W k-slice [rb*32,+32) of cls chunk cb -> Wt (st_agent),
//       bump aflag[cb]  (chunk ready when aflag[cb]==32).
//  A-x: norm+convert x rows [rb*256+cb*32, +32) -> xbf/rnorm (st_agent),
//       s-replica atomics s8[cb]; bump bflag[rb] + scnt.
//  B:   spin aflag[cb]==32 && bflag[rb]==8, then R5's proven T-stack GEMM
//       (tri-buffer LDS, depth-2 prefetch, counted vmcnt(6), XOR-swizzle,
//       setprio) + fused softmax partials (st_agent) + split-K fixup: the
//       8th-arriving block per rb spins scnt==256, reduces s8 -> LDS,
//       computes dot(x_row,s) + merges partials -> out.
// ---------------------------------------------------------------------------
#define LDSBUF 49152
#define NBLK 256

__global__ __launch_bounds__(512) void k_all(const float* __restrict__ x,
                                             const float* __restrict__ W,
                                             const float* __restrict__ bias,
                                             unsigned short* __restrict__ Wt,
                                             unsigned short* __restrict__ xbf,
                                             float* __restrict__ rnorm,
                                             float* __restrict__ s8,
                                             int* __restrict__ cnt,
                                             int* __restrict__ bflag,
                                             int* __restrict__ aflag,
                                             int* __restrict__ scnt,
                                             float* __restrict__ pm,
                                             float* __restrict__ pz,
                                             float* __restrict__ ps,
                                             float* __restrict__ out) {
  __shared__ __align__(16) char lds[147456];
  __shared__ int lastflag;

  int tid = threadIdx.x;
  int lane = tid & 63;
  int wid = tid >> 6;  // 0..7
  int b = blockIdx.x;
  int cb = b & 7;
  int rb = b >> 3;
  int C0 = cb * 128;
  int R0 = rb * 256;

  // ===== A-W: transpose W k-slice -> Wt cls rows [C0,C0+128), k [rb*32,+32)
  {
    float* tileW = (float*)lds;  // [32][136] f32
    int kk = tid >> 4;   // 0..31
    int jj = tid & 15;   // 0..15
    int k0 = rb * 32;
    int cbase = C0 + jj * 8;
    const float* wrow = W + (size_t)(k0 + kk) * 1000;
    float w[8];
    if (cbase + 7 < 1000) {
      float4 a0 = *(const float4*)(wrow + cbase);
      float4 a1 = *(const float4*)(wrow + cbase + 4);
      w[0] = a0.x; w[1] = a0.y; w[2] = a0.z; w[3] = a0.w;
      w[4] = a1.x; w[5] = a1.y; w[6] = a1.z; w[7] = a1.w;
    } else {
#pragma unroll
      for (int e = 0; e < 8; ++e)
        w[e] = (cbase + e < 1000) ? wrow[cbase + e] : 0.f;
    }
#pragma unroll
    for (int e = 0; e < 8; ++e) tileW[kk * 136 + jj * 8 + e] = w[e];
    __syncthreads();
    int cl = tid >> 2;  // 0..127
    int q = tid & 3;    // 0..3
    unsigned short hs[8];
#pragma unroll
    for (int e = 0; e < 8; ++e)
      hs[e] = f2bf(tileW[(q * 8 + e) * 136 + cl]);
    unsigned long long p0 = (unsigned long long)hs[0] |
                            ((unsigned long long)hs[1] << 16) |
                            ((unsigned long long)hs[2] << 32) |
                            ((unsigned long long)hs[3] << 48);
    unsigned long long p1 = (unsigned long long)hs[4] |
                            ((unsigned long long)hs[5] << 16) |
                            ((unsigned long long)hs[6] << 32) |
                            ((unsigned long long)hs[7] << 48);
    unsigned long long* dst =
        (unsigned long long*)(Wt + (size_t)(C0 + cl) * 1024 + k0 + q * 8);
    st_agent64(dst, p0);
    st_agent64(dst + 1, p1);
  }
  asm volatile("s_waitcnt vmcnt(0)" ::: "memory");
  __syncthreads();
  if (tid == 0) atomicAdd(aflag + cb, 1);

  // ===== A-x: norm/convert rows [R0 + cb*32, +32), s partial to s8[cb]
  {
    float (*sblk)[1024] = (float(*)[1024])(lds + 17408);  // 8x1024 f32
    int row0 = R0 + cb * 32;
    float4 sacc[4];
#pragma unroll
    for (int j = 0; j < 4; ++j) sacc[j] = make_float4(0.f, 0.f, 0.f, 0.f);
#pragma unroll
    for (int r = 0; r < 4; ++r) {
      int row = row0 + wid * 4 + r;
      const float4* xr = (const float4*)(x + (size_t)row * 1024);
      float4 v[4];
      float ss = 0.f;
#pragma unroll
      for (int j = 0; j < 4; ++j) {
        v[j] = xr[lane + j * 64];
        ss += v[j].x * v[j].x + v[j].y * v[j].y + v[j].z * v[j].z + v[j].w * v[j].w;
      }
#pragma unroll
      for (int m = 1; m < 64; m <<= 1) ss += __shfl_xor(ss, m);
      float rn = 1.f / fmaxf(sqrtf(ss), 1e-8f);
      if (lane == 0) st_agent(&rnorm[row], rn);
      unsigned long long* xrow64 = (unsigned long long*)(xbf + (size_t)row * 1024);
#pragma unroll
      for (int j = 0; j < 4; ++j) {
        unsigned long long pk = (unsigned long long)f2bf(v[j].x) |
                                ((unsigned long long)f2bf(v[j].y) << 16) |
                                ((unsigned long long)f2bf(v[j].z) << 32) |
                                ((unsigned long long)f2bf(v[j].w) << 48);
        st_agent64(xrow64 + lane + j * 64, pk);
        sacc[j].x += v[j].x * rn; sacc[j].y += v[j].y * rn;
        sacc[j].z += v[j].z * rn; sacc[j].w += v[j].w * rn;
      }
    }
#pragma unroll
    for (int j = 0; j < 4; ++j) ((float4*)sblk[wid])[j * 64 + lane] = sacc[j];
    __syncthreads();
    for (int d = tid; d < 1024; d += 512) {
      float t = 0.f;
#pragma unroll
      for (int w = 0; w < 8; ++w) t += sblk[w][d];
      atomicAdd(&s8[cb * 1024 + d], t);
    }
  }
  asm volatile("s_waitcnt vmcnt(0)" ::: "memory");
  __syncthreads();
  if (tid == 0) {
    atomicAdd(bflag + rb, 1);
    atomicAdd(scnt, 1);
  }

  // ===== Spin on own dependencies (no cache maintenance, flags monotone)
  if (tid == 0) {
    while (ld_agent_i(aflag + cb) < 32) __builtin_amdgcn_s_sleep(8);
    while (ld_agent_i(bflag + rb) < 8) __builtin_amdgcn_s_sleep(8);
  }
  __syncthreads();
  asm volatile("" ::: "memory");

  // ===== Phase B: GEMM (cls x rows) + softmax partials =====
  int wc = wid & 1;
  int wr = wid >> 1;

  float bv[4][4];
#pragma unroll
  for (int mf = 0; mf < 4; ++mf)
#pragma unroll
    for (int q = 0; q < 4; ++q) {
      int cls_g = C0 + wc * 64 + mf * 16 + (lane >> 4) * 4 + q;
      bv[mf][q] = (cls_g < 1000) ? bias[cls_g] : -1e30f;
    }
  f32x4 acc[4][4];
#pragma unroll
  for (int mf = 0; mf < 4; ++mf)
#pragma unroll
    for (int nf = 0; nf < 4; ++nf)
#pragma unroll
      for (int q = 0; q < 4; ++q) acc[mf][nf][q] = bv[mf][q];

  const char* gA = (const char*)(Wt + (size_t)C0 * 1024);
  const char* gB = (const char*)(xbf + (size_t)R0 * 1024);
  int grow = lane >> 3;
  int gswz = ((lane & 7) ^ grow) << 4;

#define STA(kt, bb, r)                                                         \
  gload_lds16(gA + (size_t)((r) * 64 + wid * 8 + grow) * 2048 + (kt) * 128 +   \
                  gswz,                                                        \
              lds + (bb) * LDSBUF + (r) * 8192 + wid * 1024)
#define STB(kt, bb, r)                                                         \
  gload_lds16(gB + (size_t)((r) * 64 + wid * 8 + grow) * 2048 + (kt) * 128 +   \
                  gswz,                                                        \
              lds + (bb) * LDSBUF + 16384 + (r) * 8192 + wid * 1024)

  STA(0, 0, 0); STA(0, 0, 1); STB(0, 0, 0); STB(0, 0, 1); STB(0, 0, 2); STB(0, 0, 3);
  STA(1, 1, 0); STA(1, 1, 1); STB(1, 1, 0); STB(1, 1, 1); STB(1, 1, 2); STB(1, 1, 3);

  int rsw = (lane & 7) << 4;
  int kcol = (lane >> 4) * 16;

  auto ktile = [&](const char* A, const char* B, int nt, int nb, bool pf) {
    if (pf) { STA(nt, nb, 0); STA(nt, nb, 1); }
    bf16x8 a[4][2];
#pragma unroll
    for (int mf = 0; mf < 4; ++mf)
#pragma unroll
      for (int ks = 0; ks < 2; ++ks)
        a[mf][ks] = *(const bf16x8*)(A + (wc * 64 + mf * 16 + (lane & 15)) * 128 +
                                     ((ks * 64 + kcol) ^ rsw));
    {
      bf16x8 b0[2];
#pragma unroll
      for (int ks = 0; ks < 2; ++ks)
        b0[ks] = *(const bf16x8*)(B + (wr * 64 + 0 * 16 + (lane & 15)) * 128 +
                                  ((ks * 64 + kcol) ^ rsw));
      __builtin_amdgcn_s_setprio(1);
#pragma unroll
      for (int ks = 0; ks < 2; ++ks)
#pragma unroll
        for (int mf = 0; mf < 4; ++mf)
          acc[mf][0] = __builtin_amdgcn_mfma_f32_16x16x32_bf16(a[mf][ks], b0[ks],
                                                               acc[mf][0], 0, 0, 0);
      __builtin_amdgcn_s_setprio(0);
    }
    if (pf) { STB(nt, nb, 0); STB(nt, nb, 1); }
    {
      bf16x8 b1[2];
#pragma unroll
      for (int ks = 0; ks < 2; ++ks)
        b1[ks] = *(const bf16x8*)(B + (wr * 64 + 1 * 16 + (lane & 15)) * 128 +
                                  ((ks * 64 + kcol) ^ rsw));
      __builtin_amdgcn_s_setprio(1);
#pragma unroll
      for (int ks = 0; ks < 2; ++ks)
#pragma unroll
        for (int mf = 0; mf < 4; ++mf)
          acc[mf][1] = __builtin_amdgcn_mfma_f32_16x16x32_bf16(a[mf][ks], b1[ks],
                                                               acc[mf][1], 0, 0, 0);
      __builtin_amdgcn_s_setprio(0);
    }
    if (pf) { STB(nt, nb, 2); STB(nt, nb, 3); }
    {
      bf16x8 b2[2];
#pragma unroll
      for (int ks = 0; ks < 2; ++ks)
        b2[ks] = *(const bf16x8*)(B + (wr * 64 + 2 * 16 + (lane & 15)) * 128 +
                                  ((ks * 64 + kcol) ^ rsw));
      __builtin_amdgcn_s_setprio(1);
#pragma unroll
      for (int ks = 0; ks < 2; ++ks)
#pragma unroll
        for (int mf = 0; mf < 4; ++mf)
          acc[mf][2] = __builtin_amdgcn_mfma_f32_16x16x32_bf16(a[mf][ks], b2[ks],
                                                               acc[mf][2], 0, 0, 0);
      __builtin_amdgcn_s_setprio(0);
    }
    {
      bf16x8 b3[2];
#pragma unroll
      for (int ks = 0; ks < 2; ++ks)
        b3[ks] = *(const bf16x8*)(B + (wr * 64 + 3 * 16 + (lane & 15)) * 128 +
                                  ((ks * 64 + kcol) ^ rsw));
      __builtin_amdgcn_s_setprio(1);
#pragma unroll
      for (int ks = 0; ks < 2; ++ks)
#pragma unroll
        for (int mf = 0; mf < 4; ++mf)
          acc[mf][3] = __builtin_amdgcn_mfma_f32_16x16x32_bf16(a[mf][ks], b3[ks],
                                                               acc[mf][3], 0, 0, 0);
      __builtin_amdgcn_s_setprio(0);
    }
  };

  for (int t = 0; t < 15; ++t) {
    asm volatile("s_waitcnt vmcnt(6)" ::: "memory");
    __builtin_amdgcn_s_barrier();
    asm volatile("" ::: "memory");
    const char* A = lds + (t % 3) * LDSBUF;
    ktile(A, A + 16384, t + 2, (t + 2) % 3, t < 14);
  }
  asm volatile("s_waitcnt vmcnt(0)" ::: "memory");
  __builtin_amdgcn_s_barrier();
  asm volatile("" ::: "memory");
  {
    const char* A = lds + (15 % 3) * LDSBUF;
    ktile(A, A + 16384, 0, 0, false);
  }

  // softmax partial stats (per wave 64 cls), merge wc halves via LDS
  __syncthreads();
  float* mm = (float*)lds;
  float* zz = mm + 512;
  float* sv = zz + 512;
#pragma unroll
  for (int nf = 0; nf < 4; ++nf) {
    float m1 = -1e30f;
#pragma unroll
    for (int mf = 0; mf < 4; ++mf)
#pragma unroll
      for (int q = 0; q < 4; ++q) m1 = fmaxf(m1, acc[mf][nf][q]);
    m1 = fmaxf(m1, __shfl_xor(m1, 16));
    m1 = fmaxf(m1, __shfl_xor(m1, 32));
    float z1 = 0.f, s1 = 0.f;
#pragma unroll
    for (int mf = 0; mf < 4; ++mf)
#pragma unroll
      for (int q = 0; q < 4; ++q) {
        float tt = acc[mf][nf][q] - m1;
        float e = expf(tt);
        z1 += e;
        s1 += e * tt;
      }
    z1 += __shfl_xor(z1, 16); z1 += __shfl_xor(z1, 32);
    s1 += __shfl_xor(s1, 16); s1 += __shfl_xor(s1, 32);
    if (lane < 16) {
      int r = wr * 64 + nf * 16 + lane;
      mm[wc * 256 + r] = m1;
      zz[wc * 256 + r] = z1;
      sv[wc * 256 + r] = s1;
    }
  }
  __syncthreads();
  if (tid < 256) {
    float m0 = mm[tid], mA = mm[256 + tid];
    float z0 = zz[tid], zA = zz[256 + tid];
    float s0 = sv[tid], sA = sv[256 + tid];
    float M = fmaxf(m0, mA);
    float e0 = expf(m0 - M), e1 = expf(mA - M);
    float Z = z0 * e0 + zA * e1;
    float S = e0 * (s0 + (m0 - M) * z0) + e1 * (sA + (mA - M) * zA);
    size_t o = (size_t)cb * 8192 + R0 + tid;
    st_agent(&pm[o], M);
    st_agent(&pz[o], Z);
    st_agent(&ps[o], S);
  }

  // ===== Fence-free split-K fixup (8th-arriving block per rb) =====
  asm volatile("s_waitcnt vmcnt(0)" ::: "memory");
  __syncthreads();
  if (tid == 0) lastflag = (atomicAdd(&cnt[rb], 1) == 7) ? 1 : 0;
  __syncthreads();
  if (lastflag) {
    if (tid == 0)
      while (ld_agent_i(scnt) < NBLK) __builtin_amdgcn_s_sleep(8);
    __syncthreads();
    // reduce s replicas into LDS
    float* sld = (float*)(lds + 4096);
    for (int d = tid; d < 1024; d += 512) {
      float t = 0.f;
#pragma unroll
      for (int r = 0; r < 8; ++r) t += ld_agent(&s8[r * 1024 + d]);
      sld[d] = t;
    }
    __syncthreads();
    // dot(x_row, s): 2 threads/row, xbf panel is L2-hot from the GEMM
    float* dotl = (float*)(lds + 8192);
    int rr = tid >> 1, half = tid & 1;
    int row = R0 + rr;
    const bf16x8* xr = (const bf16x8*)(xbf + (size_t)row * 1024 + half * 512);
    const float4* sp = (const float4*)(sld + half * 512);
    float d = 0.f;
#pragma unroll 8
    for (int j = 0; j < 64; ++j) {
      bf16x8 v = xr[j];
      float4 sa = sp[j * 2], sb = sp[j * 2 + 1];
      d += bf2f((unsigned short)v[0]) * sa.x + bf2f((unsigned short)v[1]) * sa.y +
           bf2f((unsigned short)v[2]) * sa.z + bf2f((unsigned short)v[3]) * sa.w +
           bf2f((unsigned short)v[4]) * sb.x + bf2f((unsigned short)v[5]) * sb.y +
           bf2f((unsigned short)v[6]) * sb.z + bf2f((unsigned short)v[7]) * sb.w;
    }
    d += __shfl_xor(d, 1);
    if (half == 0) dotl[rr] = d;
    __syncthreads();
    if (tid < 256) {
      int orow = R0 + tid;
      float mv[8], zv[8], svv[8];
      float M = -1e30f;
#pragma unroll
      for (int c = 0; c < 8; ++c) {
        mv[c] = ld_agent(&pm[(size_t)c * 8192 + orow]);
        zv[c] = ld_agent(&pz[(size_t)c * 8192 + orow]);
        svv[c] = ld_agent(&ps[(size_t)c * 8192 + orow]);
        M = fmaxf(M, mv[c]);
      }
      float Z = 0.f, S = 0.f;
#pragma unroll
      for (int c = 0; c < 8; ++c) {
        float e = expf(mv[c] - M);
        Z += zv[c] * e;
        S += e * (svv[c] + (mv[c] - M) * zv[c]);
      }
      float loss = S / Z - logf(Z);
      out[orow] = loss * dotl[tid] * ld_agent(&rnorm[orow]) * (1.f / 8192.f);
    }
  }
}

// ---------------------------------------------------------------------------
extern "C" void kernel_launch(void* const* d_in, const int* in_sizes, int n_in,
                              void* d_out, int out_size, void* d_ws, size_t ws_size,
                              hipStream_t stream) {
  (void)in_sizes; (void)n_in; (void)out_size; (void)ws_size;
  const float* x = (const float*)d_in[0];
  const float* W = (const float*)d_in[1];
  const float* b = (const float*)d_in[2];
  float* out = (float*)d_out;
  char* ws = (char*)d_ws;

  unsigned short* Wt = (unsigned short*)(ws + 0);           // 2 MiB
  unsigned short* xbf = (unsigned short*)(ws + 2097152);    // 16 MiB
  float* rnorm = (float*)(ws + 18874368);                   // 32 KiB
  float* pm = (float*)(ws + 18907136);                      // 256 KiB
  float* pz = (float*)(ws + 18907136 + 262144);
  float* ps = (float*)(ws + 18907136 + 524288);
  // zeroed region Z:
  char* Z = ws + 19693568;
  float* s8 = (float*)(Z);                                  // 8*1024*4 = 32 KiB
  int* cnt = (int*)(Z + 32768);                             // 32 ints
  int* bflag = (int*)(Z + 32896);                           // 32 ints
  int* aflag = (int*)(Z + 33024);                           // 8 ints
  int* scnt = (int*)(Z + 33056);                            // 1 int

  hipMemsetAsync(Z, 0, 33280, stream);
  k_all<<<NBLK, 512, 0, stream>>>(x, W, b, Wt, xbf, rnorm, s8, cnt, bflag,
                                  aflag, scnt, pm, pz, ps, out);
}

// Round 8
// 59.516 us; speedup vs baseline: 1.7114x; 1.3202x over previous
//
#include <hip/hip_runtime.h>
#include <hip/hip_bf16.h>
#include <cstdint>
#include <cstddef>

typedef __attribute__((ext_vector_type(8))) short bf16x8;
typedef __attribute__((ext_vector_type(4))) float f32x4;

__device__ __forceinline__ unsigned short f2bf(float f) {
  union { float f; unsigned u; } v; v.f = f;
  unsigned r = v.u + 0x7FFFu + ((v.u >> 16) & 1u);
  return (unsigned short)(r >> 16);
}

__device__ __forceinline__ float bf2f(unsigned short h) {
  union { float f; unsigned u; } c; c.u = ((unsigned)h) << 16;
  return c.f;
}

__device__ __forceinline__ void gload_lds16(const void* g, void* l) {
  __builtin_amdgcn_global_load_lds(
      (const __attribute__((address_space(1))) unsigned int*)g,
      (__attribute__((address_space(3))) unsigned int*)l, 16, 0, 0);
}

__device__ __forceinline__ void st_agent(float* p, float v) {
  __hip_atomic_store(p, v, __ATOMIC_RELAXED, __HIP_MEMORY_SCOPE_AGENT);
}
__device__ __forceinline__ float ld_agent(const float* p) {
  return __hip_atomic_load(p, __ATOMIC_RELAXED, __HIP_MEMORY_SCOPE_AGENT);
}

// ---------------------------------------------------------------------------
// K01 fused: blocks [0,256): W transpose->bf16 Wt[1024cls][1024k] (pad 0,
//            row 1000 reserved for s). blocks [256,768): per-row rnorm,
//            x->bf16, s += xn (device atomics). Last-arriving norm block
//            (fence-free counter protocol) writes bf16(s) into Wt row 1000.
// ---------------------------------------------------------------------------
__global__ __launch_bounds__(256) void k01_prep(const float* __restrict__ W,
                                                unsigned short* __restrict__ Wt,
                                                const float* __restrict__ x,
                                                unsigned short* __restrict__ xbf,
                                                float* __restrict__ rnorm,
                                                float* __restrict__ s,
                                                int* __restrict__ cnt2) {
  __shared__ __align__(16) char sm[16640];
  __shared__ int lf;
  int tid = threadIdx.x;
  if (blockIdx.x < 256) {
    float (*tile)[65] = (float(*)[65])sm;
    int k0 = (blockIdx.x & 15) * 64;
    int c0 = (blockIdx.x >> 4) * 64;
    int tx = tid & 63;
    int ty = tid >> 6;
#pragma unroll
    for (int i = 0; i < 16; ++i) {
      int r = i * 4 + ty;
      int c = c0 + tx;
      tile[r][tx] = (c < 1000) ? W[(size_t)(k0 + r) * 1000 + c] : 0.f;
    }
    __syncthreads();
#pragma unroll
    for (int i = 0; i < 16; ++i) {
      int ct = i * 4 + ty;
      int cg = c0 + ct;
      if (cg != 1000)
        Wt[(size_t)cg * 1024 + (k0 + tx)] = f2bf(tile[tx][ct]);
    }
    return;
  }
  float (*sblk)[1024] = (float(*)[1024])sm;
  int bid = blockIdx.x - 256;
  int wid = tid >> 6, lane = tid & 63;
  float4 sacc[4];
#pragma unroll
  for (int j = 0; j < 4; ++j) sacc[j] = make_float4(0.f, 0.f, 0.f, 0.f);
#pragma unroll
  for (int r = 0; r < 4; ++r) {
    int row = bid * 16 + wid * 4 + r;
    const float4* xr = (const float4*)(x + (size_t)row * 1024);
    float4 v[4];
    float ss = 0.f;
#pragma unroll
    for (int j = 0; j < 4; ++j) {
      v[j] = xr[lane + j * 64];
      ss += v[j].x * v[j].x + v[j].y * v[j].y + v[j].z * v[j].z + v[j].w * v[j].w;
    }
#pragma unroll
    for (int m = 1; m < 64; m <<= 1) ss += __shfl_xor(ss, m);
    float rn = 1.f / fmaxf(sqrtf(ss), 1e-8f);
    if (lane == 0) rnorm[row] = rn;
#pragma unroll
    for (int j = 0; j < 4; ++j) {
      ushort4 hv;
      hv.x = f2bf(v[j].x); hv.y = f2bf(v[j].y);
      hv.z = f2bf(v[j].z); hv.w = f2bf(v[j].w);
      ((ushort4*)(xbf + (size_t)row * 1024))[lane + j * 64] = hv;
      sacc[j].x += v[j].x * rn; sacc[j].y += v[j].y * rn;
      sacc[j].z += v[j].z * rn; sacc[j].w += v[j].w * rn;
    }
  }
#pragma unroll
  for (int j = 0; j < 4; ++j) ((float4*)sblk[wid])[j * 64 + lane] = sacc[j];
  __syncthreads();
  for (int d = tid; d < 1024; d += 256) {
    float t = sblk[0][d] + sblk[1][d] + sblk[2][d] + sblk[3][d];
    atomicAdd(&s[d], t);  // device-scope RMW at coherence point
  }
  // Ensure own RMWs retired, then count. No cache-maintenance fences.
  asm volatile("s_waitcnt vmcnt(0)" ::: "memory");
  __syncthreads();
  if (tid == 0) lf = (atomicAdd(cnt2, 1) == 511) ? 1 : 0;
  __syncthreads();
  if (lf) {
    ushort4 h;
    h.x = f2bf(ld_agent(&s[tid * 4 + 0]));
    h.y = f2bf(ld_agent(&s[tid * 4 + 1]));
    h.z = f2bf(ld_agent(&s[tid * 4 + 2]));
    h.w = f2bf(ld_agent(&s[tid * 4 + 3]));
    ((ushort4*)(Wt + (size_t)1000 * 1024))[tid] = h;  // kernel-boundary flush
  }
}

// ---------------------------------------------------------------------------
// K3: bf16 MFMA GEMM (cls x rows) + fused softmax partials + split-K fixup.
// Block = 128 cls x 256 rows, BK=64; grid 256; 512 thr (8 waves, 2c x 4r).
// *** R8 single-variable change vs R5: block-index factorization swapped to
//     cb = b>>5, rb = b&31.  Now b mod 8 == rb mod 8, so the 8 blocks that
//     share one 512KB xbf row-panel all land on ONE XCD -> panel fetched
//     into that L2 once (L2-hit for the other 7) instead of 8 L3 fetches.
//     Per-XCD L2 residency: 4 panels (2MB) + Wt (2MB) = 4MB = exact fit. ***
// Tri-buffered LDS, depth-2 prefetch, counted vmcnt(6); tile-15 peeled
// behind vmcnt(0). XOR-swizzle via inverse-swizzled global source.
// Class 1000 = dot(x_row, s) -> pd, masked from stats. Fence-free fixup.
// ---------------------------------------------------------------------------
#define LDSBUF 49152

__global__ __launch_bounds__(512) void k3_gemm(const unsigned short* __restrict__ xbf,
                                               const unsigned short* __restrict__ wt,
                                               const float* __restrict__ bias,
                                               const float* __restrict__ rnorm,
                                               float* __restrict__ pm,
                                               float* __restrict__ pz,
                                               float* __restrict__ ps,
                                               float* __restrict__ pd,
                                               int* __restrict__ cnt,
                                               float* __restrict__ out) {
  __shared__ __align__(16) char lds[147456];
  __shared__ int lastflag;

  int tid = threadIdx.x;
  int lane = tid & 63;
  int wid = tid >> 6;
  int wc = wid & 1;
  int wr = wid >> 1;
  int cb = blockIdx.x >> 5;   // cls chunk (0..7): same-rb blocks share an XCD
  int rb = blockIdx.x & 31;   // row block (0..31) -> XCD = rb % 8
  int C0 = cb * 128;
  int R0 = rb * 256;

  float bv[4][4];
#pragma unroll
  for (int mf = 0; mf < 4; ++mf)
#pragma unroll
    for (int q = 0; q < 4; ++q) {
      int cls_g = C0 + wc * 64 + mf * 16 + (lane >> 4) * 4 + q;
      bv[mf][q] = (cls_g < 1000) ? bias[cls_g] : ((cls_g == 1000) ? 0.f : -1e30f);
    }
  f32x4 acc[4][4];
#pragma unroll
  for (int mf = 0; mf < 4; ++mf)
#pragma unroll
    for (int nf = 0; nf < 4; ++nf)
#pragma unroll
      for (int q = 0; q < 4; ++q) acc[mf][nf][q] = bv[mf][q];

  const char* gA = (const char*)(wt + (size_t)C0 * 1024);
  const char* gB = (const char*)(xbf + (size_t)R0 * 1024);
  int grow = lane >> 3;
  int gswz = ((lane & 7) ^ grow) << 4;

#define STA(kt, b, r)                                                          \
  gload_lds16(gA + (size_t)((r) * 64 + wid * 8 + grow) * 2048 + (kt) * 128 +   \
                  gswz,                                                        \
              lds + (b) * LDSBUF + (r) * 8192 + wid * 1024)
#define STB(kt, b, r)                                                          \
  gload_lds16(gB + (size_t)((r) * 64 + wid * 8 + grow) * 2048 + (kt) * 128 +   \
                  gswz,                                                        \
              lds + (b) * LDSBUF + 16384 + (r) * 8192 + wid * 1024)

  STA(0, 0, 0); STA(0, 0, 1); STB(0, 0, 0); STB(0, 0, 1); STB(0, 0, 2); STB(0, 0, 3);
  STA(1, 1, 0); STA(1, 1, 1); STB(1, 1, 0); STB(1, 1, 1); STB(1, 1, 2); STB(1, 1, 3);

  int rsw = (lane & 7) << 4;
  int kcol = (lane >> 4) * 16;

  auto ktile = [&](const char* A, const char* B, int nt, int nb, bool pf) {
    if (pf) { STA(nt, nb, 0); STA(nt, nb, 1); }
    bf16x8 a[4][2];
#pragma unroll
    for (int mf = 0; mf < 4; ++mf)
#pragma unroll
      for (int ks = 0; ks < 2; ++ks)
        a[mf][ks] = *(const bf16x8*)(A + (wc * 64 + mf * 16 + (lane & 15)) * 128 +
                                     ((ks * 64 + kcol) ^ rsw));
    {
      bf16x8 b0[2];
#pragma unroll
      for (int ks = 0; ks < 2; ++ks)
        b0[ks] = *(const bf16x8*)(B + (wr * 64 + 0 * 16 + (lane & 15)) * 128 +
                                  ((ks * 64 + kcol) ^ rsw));
      __builtin_amdgcn_s_setprio(1);
#pragma unroll
      for (int ks = 0; ks < 2; ++ks)
#pragma unroll
        for (int mf = 0; mf < 4; ++mf)
          acc[mf][0] = __builtin_amdgcn_mfma_f32_16x16x32_bf16(a[mf][ks], b0[ks],
                                                               acc[mf][0], 0, 0, 0);
      __builtin_amdgcn_s_setprio(0);
    }
    if (pf) { STB(nt, nb, 0); STB(nt, nb, 1); }
    {
      bf16x8 b1[2];
#pragma unroll
      for (int ks = 0; ks < 2; ++ks)
        b1[ks] = *(const bf16x8*)(B + (wr * 64 + 1 * 16 + (lane & 15)) * 128 +
                                  ((ks * 64 + kcol) ^ rsw));
      __builtin_amdgcn_s_setprio(1);
#pragma unroll
      for (int ks = 0; ks < 2; ++ks)
#pragma unroll
        for (int mf = 0; mf < 4; ++mf)
          acc[mf][1] = __builtin_amdgcn_mfma_f32_16x16x32_bf16(a[mf][ks], b1[ks],
                                                               acc[mf][1], 0, 0, 0);
      __builtin_amdgcn_s_setprio(0);
    }
    if (pf) { STB(nt, nb, 2); STB(nt, nb, 3); }
    {
      bf16x8 b2[2];
#pragma unroll
      for (int ks = 0; ks < 2; ++ks)
        b2[ks] = *(const bf16x8*)(B + (wr * 64 + 2 * 16 + (lane & 15)) * 128 +
                                  ((ks * 64 + kcol) ^ rsw));
      __builtin_amdgcn_s_setprio(1);
#pragma unroll
      for (int ks = 0; ks < 2; ++ks)
#pragma unroll
        for (int mf = 0; mf < 4; ++mf)
          acc[mf][2] = __builtin_amdgcn_mfma_f32_16x16x32_bf16(a[mf][ks], b2[ks],
                                                               acc[mf][2], 0, 0, 0);
      __builtin_amdgcn_s_setprio(0);
    }
    {
      bf16x8 b3[2];
#pragma unroll
      for (int ks = 0; ks < 2; ++ks)
        b3[ks] = *(const bf16x8*)(B + (wr * 64 + 3 * 16 + (lane & 15)) * 128 +
                                  ((ks * 64 + kcol) ^ rsw));
      __builtin_amdgcn_s_setprio(1);
#pragma unroll
      for (int ks = 0; ks < 2; ++ks)
#pragma unroll
        for (int mf = 0; mf < 4; ++mf)
          acc[mf][3] = __builtin_amdgcn_mfma_f32_16x16x32_bf16(a[mf][ks], b3[ks],
                                                               acc[mf][3], 0, 0, 0);
      __builtin_amdgcn_s_setprio(0);
    }
  };

  for (int t = 0; t < 15; ++t) {
    asm volatile("s_waitcnt vmcnt(6)" ::: "memory");
    __builtin_amdgcn_s_barrier();
    asm volatile("" ::: "memory");
    const char* A = lds + (t % 3) * LDSBUF;
    ktile(A, A + 16384, t + 2, (t + 2) % 3, t < 14);
  }
  // peeled tile 15: only its own 6 loads outstanding -> full drain
  asm volatile("s_waitcnt vmcnt(0)" ::: "memory");
  __builtin_amdgcn_s_barrier();
  asm volatile("" ::: "memory");
  {
    const char* A = lds + (15 % 3) * LDSBUF;
    ktile(A, A + 16384, 0, 0, false);
  }

  // Extract class-1000 dot -> pd (agent store), mask from stats.
  if (cb == 7 && wc == 1 && ((lane >> 4) == 2)) {
#pragma unroll
    for (int nf = 0; nf < 4; ++nf) {
      int r = wr * 64 + nf * 16 + (lane & 15);
      st_agent(&pd[(size_t)rb * 256 + r], acc[2][nf][0]);
      acc[2][nf][0] = -1e30f;
    }
  }

  __syncthreads();
  float* mm = (float*)lds;
  float* zz = mm + 512;
  float* sv = zz + 512;
#pragma unroll
  for (int nf = 0; nf < 4; ++nf) {
    float m1 = -1e30f;
#pragma unroll
    for (int mf = 0; mf < 4; ++mf)
#pragma unroll
      for (int q = 0; q < 4; ++q) m1 = fmaxf(m1, acc[mf][nf][q]);
    m1 = fmaxf(m1, __shfl_xor(m1, 16));
    m1 = fmaxf(m1, __shfl_xor(m1, 32));
    float z1 = 0.f, s1 = 0.f;
#pragma unroll
    for (int mf = 0; mf < 4; ++mf)
#pragma unroll
      for (int q = 0; q < 4; ++q) {
        float tt = acc[mf][nf][q] - m1;
        float e = expf(tt);
        z1 += e;
        s1 += e * tt;
      }
    z1 += __shfl_xor(z1, 16); z1 += __shfl_xor(z1, 32);
    s1 += __shfl_xor(s1, 16); s1 += __shfl_xor(s1, 32);
    if (lane < 16) {
      int r = wr * 64 + nf * 16 + lane;
      mm[wc * 256 + r] = m1;
      zz[wc * 256 + r] = z1;
      sv[wc * 256 + r] = s1;
    }
  }
  __syncthreads();
  if (tid < 256) {
    float m0 = mm[tid], mA = mm[256 + tid];
    float z0 = zz[tid], zA = zz[256 + tid];
    float s0 = sv[tid], sA = sv[256 + tid];
    float M = fmaxf(m0, mA);
    float e0 = expf(m0 - M), e1 = expf(mA - M);
    float Z = z0 * e0 + zA * e1;
    float S = e0 * (s0 + (m0 - M) * z0) + e1 * (sA + (mA - M) * zA);
    size_t o = (size_t)cb * 8192 + R0 + tid;
    st_agent(&pm[o], M);
    st_agent(&pz[o], Z);
    st_agent(&ps[o], S);
  }

  // Fence-free split-K fixup: own agent-stores retired -> count -> last merges.
  asm volatile("s_waitcnt vmcnt(0)" ::: "memory");
  __syncthreads();
  if (tid == 0) lastflag = (atomicAdd(&cnt[rb], 1) == 7) ? 1 : 0;
  __syncthreads();
  if (lastflag && tid < 256) {
    int row = R0 + tid;
    float mv[8], zv[8], svv[8];
    float M = -1e30f;
#pragma unroll
    for (int c = 0; c < 8; ++c) {
      mv[c] = ld_agent(&pm[(size_t)c * 8192 + row]);
      zv[c] = ld_agent(&pz[(size_t)c * 8192 + row]);
      svv[c] = ld_agent(&ps[(size_t)c * 8192 + row]);
      M = fmaxf(M, mv[c]);
    }
    float Z = 0.f, S = 0.f;
#pragma unroll
    for (int c = 0; c < 8; ++c) {
      float e = expf(mv[c] - M);
      Z += zv[c] * e;
      S += e * (svv[c] + (mv[c] - M) * zv[c]);
    }
    float loss = S / Z - logf(Z);
    float dotv = ld_agent(&pd[(size_t)rb * 256 + tid]);
    out[row] = loss * dotv * rnorm[row] * (1.f / 8192.f);
  }
}

// ---------------------------------------------------------------------------
extern "C" void kernel_launch(void* const* d_in, const int* in_sizes, int n_in,
                              void* d_out, int out_size, void* d_ws, size_t ws_size,
                              hipStream_t stream) {
  (void)in_sizes; (void)n_in; (void)out_size; (void)ws_size;
  const float* x = (const float*)d_in[0];
  const float* W = (const float*)d_in[1];
  const float* b = (const float*)d_in[2];
  float* out = (float*)d_out;
  char* ws = (char*)d_ws;

  unsigned short* Wt = (unsigned short*)(ws + 0);           // 2 MiB
  unsigned short* xbf = (unsigned short*)(ws + 2097152);    // 16 MiB
  float* rnorm = (float*)(ws + 18874368);                   // 32 KiB
  float* s = (float*)(ws + 18907136);                       // 4 KiB
  int* cnt2 = (int*)(ws + 18911232);                        // 4 B
  int* cnt = (int*)(ws + 18911236);                         // 128 B
  float* pm = (float*)(ws + 18915328);                      // 256 KiB
  float* pz = (float*)(ws + 18915328 + 262144);
  float* ps = (float*)(ws + 18915328 + 524288);
  float* pd = (float*)(ws + 18915328 + 786432);             // 32 KiB

  hipMemsetAsync(s, 0, 8192, stream);  // covers s + cnt2 + cnt
  k01_prep<<<768, 256, 0, stream>>>(W, Wt, x, xbf, rnorm, s, cnt2);
  k3_gemm<<<256, 512, 0, stream>>>(xbf, Wt, b, rnorm, pm, pz, ps, pd, cnt, out);
}